// Round 1
// baseline (258.431 us; speedup 1.0000x reference)
//
#include <hip/hip_runtime.h>

#define CAPS_EPS 1e-9f

// One workgroup (256 threads) per output spatial position (b,h,w).
// tid = n*16 + c  (n = output capsule 0..15, c = input channel 0..15, c lane-fast)
// Each thread owns votes V[k][d] for its (n,c) across k=0..8 kernel positions, d=0..15.
__global__ __launch_bounds__(256, 2)
void caps_route(const float* __restrict__ poses,   // [4][32][32][16][4][4]
                const float* __restrict__ kern,    // [16][3][3][16][4][4]
                float* __restrict__ out)           // poses 921600 | acts 57600
{
    const int pos = blockIdx.x;            // 0..3599
    const int b   = pos / 900;
    const int hw  = pos % 900;
    const int h   = hw / 30;
    const int w   = hw % 30;

    const int tid = (int)threadIdx.x;
    const int c   = tid & 15;              // input channel (lane-fast)
    const int n   = tid >> 4;              // output capsule

    // pose tile: [k][c][4 float4], granule-swizzled to kill LDS bank conflicts
    __shared__ float4 pose_lds[9 * 64];
    __shared__ float  sb[4 * 9 * 16];      // [wave][k][c] softmax partials

    // ---------------- stage pose blocks (coalesced) ----------------
    for (int idx = tid; idx < 576; idx += 256) {
        const int k  = idx >> 6;           // 0..8
        const int r  = idx & 63;           // float4 index within 1KB segment
        const int cc = r >> 2;
        const int eq = r & 3;
        const int ki = k / 3, kj = k % 3;
        const float4* src = reinterpret_cast<const float4*>(
            poses + (size_t)(((b * 32 + h + ki) * 32) + (w + kj)) * 256);
        pose_lds[k * 64 + cc * 4 + (eq ^ ((cc >> 1) & 3))] = src[r];
    }
    __syncthreads();

    // ---------------- compute votes V[k][p*4+r] ----------------
    float V[9][16];
    const float* kb = kern + (size_t)n * 2304 + (size_t)c * 16;
    const int swz = (c >> 1) & 3;
    #pragma unroll
    for (int k = 0; k < 9; ++k) {
        float a[16], g[16];
        #pragma unroll
        for (int eq = 0; eq < 4; ++eq) {
            float4 t = pose_lds[k * 64 + c * 4 + (eq ^ swz)];
            a[eq * 4 + 0] = t.x; a[eq * 4 + 1] = t.y;
            a[eq * 4 + 2] = t.z; a[eq * 4 + 3] = t.w;
        }
        #pragma unroll
        for (int eq = 0; eq < 4; ++eq) {
            float4 t = reinterpret_cast<const float4*>(kb + k * 256)[eq];
            g[eq * 4 + 0] = t.x; g[eq * 4 + 1] = t.y;
            g[eq * 4 + 2] = t.z; g[eq * 4 + 3] = t.w;
        }
        #pragma unroll
        for (int p = 0; p < 4; ++p) {
            #pragma unroll
            for (int r = 0; r < 4; ++r) {
                float acc = a[p * 4 + 0] * g[0 * 4 + r];
                acc = fmaf(a[p * 4 + 1], g[1 * 4 + r], acc);
                acc = fmaf(a[p * 4 + 2], g[2 * 4 + r], acc);
                acc = fmaf(a[p * 4 + 3], g[3 * 4 + r], acc);
                V[k][p * 4 + r] = acc;
            }
        }
    }

    // ---------------- dynamic routing (3 iterations) ----------------
    float b_log[9];
    #pragma unroll
    for (int k = 0; k < 9; ++k) b_log[k] = 0.0f;

    float v[16];
    const int wv = tid >> 6;               // wave id 0..3

    for (int it = 0; it < 3; ++it) {
        float ck[9];
        if (it == 0) {
            // softmax of all-zero logits over 16 capsules = 1/16 exactly
            #pragma unroll
            for (int k = 0; k < 9; ++k) ck[k] = 0.0625f;
        } else {
            float eb[9], ebs[9];
            #pragma unroll
            for (int k = 0; k < 9; ++k) { eb[k] = __expf(b_log[k]); ebs[k] = eb[k]; }
            // in-wave partial sum over the wave's 4 n-values (lane bits 4,5)
            #pragma unroll
            for (int k = 0; k < 9; ++k) {
                ebs[k] += __shfl_xor(ebs[k], 16);
                ebs[k] += __shfl_xor(ebs[k], 32);
            }
            __syncthreads();   // protect sb against previous iteration's readers
            if ((tid & 63) < 16) {         // one lane per (wave, c)
                #pragma unroll
                for (int k = 0; k < 9; ++k) sb[(wv * 9 + k) * 16 + c] = ebs[k];
            }
            __syncthreads();
            #pragma unroll
            for (int k = 0; k < 9; ++k) {
                const float tot = sb[(0 * 9 + k) * 16 + c] + sb[(1 * 9 + k) * 16 + c]
                                + sb[(2 * 9 + k) * 16 + c] + sb[(3 * 9 + k) * 16 + c];
                ck[k] = eb[k] / tot;
            }
        }

        // s partial over this thread's 9 votes
        float s[16];
        #pragma unroll
        for (int d = 0; d < 16; ++d) s[d] = ck[0] * V[0][d];
        #pragma unroll
        for (int k = 1; k < 9; ++k) {
            #pragma unroll
            for (int d = 0; d < 16; ++d) s[d] = fmaf(ck[k], V[k][d], s[d]);
        }
        // butterfly all-reduce over c (lane bits 0..3) -> every lane holds s[n][:]
        #pragma unroll
        for (int m = 1; m <= 8; m <<= 1) {
            #pragma unroll
            for (int d = 0; d < 16; ++d) s[d] += __shfl_xor(s[d], m);
        }
        // squash (in-registers, redundant across the 16 c-lanes)
        float n2 = 0.0f;
        #pragma unroll
        for (int d = 0; d < 16; ++d) n2 = fmaf(s[d], s[d], n2);
        const float scale = n2 / ((1.0f + n2) * sqrtf(n2 + CAPS_EPS));
        #pragma unroll
        for (int d = 0; d < 16; ++d) v[d] = s[d] * scale;

        if (it < 2) {   // final b-update is dead in the reference
            #pragma unroll
            for (int k = 0; k < 9; ++k) {
                float dot = V[k][0] * v[0];
                #pragma unroll
                for (int d = 1; d < 16; ++d) dot = fmaf(V[k][d], v[d], dot);
                b_log[k] += dot;
            }
        }
    }

    // ---------------- outputs ----------------
    if (c == 0) {
        float4* dst = reinterpret_cast<float4*>(out + (size_t)pos * 256 + n * 16);
        dst[0] = make_float4(v[0],  v[1],  v[2],  v[3]);
        dst[1] = make_float4(v[4],  v[5],  v[6],  v[7]);
        dst[2] = make_float4(v[8],  v[9],  v[10], v[11]);
        dst[3] = make_float4(v[12], v[13], v[14], v[15]);

        float m2 = 0.0f;
        #pragma unroll
        for (int d = 0; d < 16; ++d) m2 = fmaf(v[d], v[d], m2);
        const float sc2 = m2 / ((1.0f + m2) * sqrtf(m2 + CAPS_EPS));
        out[921600 + (size_t)pos * 16 + n] = sqrtf(m2 * sc2 * sc2 + CAPS_EPS);
    }
}

extern "C" void kernel_launch(void* const* d_in, const int* in_sizes, int n_in,
                              void* d_out, int out_size, void* d_ws, size_t ws_size,
                              hipStream_t stream) {
    const float* poses = (const float*)d_in[0];
    // d_in[1] = input_activations: unused by the reference computation
    const float* kern  = (const float*)d_in[2];
    float* out = (float*)d_out;

    caps_route<<<dim3(3600), dim3(256), 0, stream>>>(poses, kern, out);
}

// Round 2
// 157.255 us; speedup vs baseline: 1.6434x; 1.6434x over previous
//
#include <hip/hip_runtime.h>

#define CAPS_EPS 1e-9f

// One workgroup (256 threads) per output spatial position (b,h,w).
// tid = n*16 + c  (n = output capsule 0..15, c = input channel 0..15, c lane-fast)
// Each thread owns votes V[k][d] for its (n,c) across k=0..8 kernel positions, d=0..15.
// __launch_bounds__(256,1): allow up to ~512 VGPRs -- V[9][16]=144 regs must stay
// in-register; capping at 128 (round 1) caused 467 MB of scratch spill traffic.
__global__ __launch_bounds__(256, 1)
void caps_route(const float* __restrict__ poses,   // [4][32][32][16][4][4]
                const float* __restrict__ kern,    // [16][3][3][16][4][4]
                float* __restrict__ out)           // poses 921600 | acts 57600
{
    const int pos = blockIdx.x;            // 0..3599
    const int b   = pos / 900;
    const int hw  = pos % 900;
    const int h   = hw / 30;
    const int w   = hw % 30;

    const int tid = (int)threadIdx.x;
    const int c   = tid & 15;              // input channel (lane-fast)
    const int n   = tid >> 4;              // output capsule

    // pose tile: [k][c][4 float4], granule-swizzled to kill LDS bank conflicts
    __shared__ float4 pose_lds[9 * 64];
    __shared__ float  sb[4 * 9 * 16];      // [wave][k][c] softmax partials

    // ---------------- stage pose blocks (coalesced) ----------------
    for (int idx = tid; idx < 576; idx += 256) {
        const int k  = idx >> 6;           // 0..8
        const int r  = idx & 63;           // float4 index within 1KB segment
        const int cc = r >> 2;
        const int eq = r & 3;
        const int ki = k / 3, kj = k % 3;
        const float4* src = reinterpret_cast<const float4*>(
            poses + (size_t)(((b * 32 + h + ki) * 32) + (w + kj)) * 256);
        pose_lds[k * 64 + cc * 4 + (eq ^ ((cc >> 1) & 3))] = src[r];
    }
    __syncthreads();

    // ---------------- compute votes V[k][p*4+r] ----------------
    float V[9][16];
    const float* kb = kern + (size_t)n * 2304 + (size_t)c * 16;
    const int swz = (c >> 1) & 3;
    #pragma unroll
    for (int k = 0; k < 9; ++k) {
        float a[16], g[16];
        #pragma unroll
        for (int eq = 0; eq < 4; ++eq) {
            float4 t = pose_lds[k * 64 + c * 4 + (eq ^ swz)];
            a[eq * 4 + 0] = t.x; a[eq * 4 + 1] = t.y;
            a[eq * 4 + 2] = t.z; a[eq * 4 + 3] = t.w;
        }
        #pragma unroll
        for (int eq = 0; eq < 4; ++eq) {
            float4 t = reinterpret_cast<const float4*>(kb + k * 256)[eq];
            g[eq * 4 + 0] = t.x; g[eq * 4 + 1] = t.y;
            g[eq * 4 + 2] = t.z; g[eq * 4 + 3] = t.w;
        }
        #pragma unroll
        for (int p = 0; p < 4; ++p) {
            #pragma unroll
            for (int r = 0; r < 4; ++r) {
                float acc = a[p * 4 + 0] * g[0 * 4 + r];
                acc = fmaf(a[p * 4 + 1], g[1 * 4 + r], acc);
                acc = fmaf(a[p * 4 + 2], g[2 * 4 + r], acc);
                acc = fmaf(a[p * 4 + 3], g[3 * 4 + r], acc);
                V[k][p * 4 + r] = acc;
            }
        }
    }

    // ---------------- dynamic routing (3 iterations) ----------------
    float b_log[9];
    #pragma unroll
    for (int k = 0; k < 9; ++k) b_log[k] = 0.0f;

    float v[16];
    const int wv = tid >> 6;               // wave id 0..3

    for (int it = 0; it < 3; ++it) {
        float ck[9];
        if (it == 0) {
            // softmax of all-zero logits over 16 capsules = 1/16 exactly
            #pragma unroll
            for (int k = 0; k < 9; ++k) ck[k] = 0.0625f;
        } else {
            float eb[9], ebs[9];
            #pragma unroll
            for (int k = 0; k < 9; ++k) { eb[k] = __expf(b_log[k]); ebs[k] = eb[k]; }
            // in-wave partial sum over the wave's 4 n-values (lane bits 4,5)
            #pragma unroll
            for (int k = 0; k < 9; ++k) {
                ebs[k] += __shfl_xor(ebs[k], 16);
                ebs[k] += __shfl_xor(ebs[k], 32);
            }
            __syncthreads();   // protect sb against previous iteration's readers
            if ((tid & 63) < 16) {         // one lane per (wave, c)
                #pragma unroll
                for (int k = 0; k < 9; ++k) sb[(wv * 9 + k) * 16 + c] = ebs[k];
            }
            __syncthreads();
            #pragma unroll
            for (int k = 0; k < 9; ++k) {
                const float tot = sb[(0 * 9 + k) * 16 + c] + sb[(1 * 9 + k) * 16 + c]
                                + sb[(2 * 9 + k) * 16 + c] + sb[(3 * 9 + k) * 16 + c];
                ck[k] = eb[k] / tot;
            }
        }

        // s partial over this thread's 9 votes
        float s[16];
        #pragma unroll
        for (int d = 0; d < 16; ++d) s[d] = ck[0] * V[0][d];
        #pragma unroll
        for (int k = 1; k < 9; ++k) {
            #pragma unroll
            for (int d = 0; d < 16; ++d) s[d] = fmaf(ck[k], V[k][d], s[d]);
        }
        // butterfly all-reduce over c (lane bits 0..3) -> every lane holds s[n][:]
        #pragma unroll
        for (int m = 1; m <= 8; m <<= 1) {
            #pragma unroll
            for (int d = 0; d < 16; ++d) s[d] += __shfl_xor(s[d], m);
        }
        // squash (in-registers, redundant across the 16 c-lanes)
        float n2 = 0.0f;
        #pragma unroll
        for (int d = 0; d < 16; ++d) n2 = fmaf(s[d], s[d], n2);
        const float scale = n2 / ((1.0f + n2) * sqrtf(n2 + CAPS_EPS));
        #pragma unroll
        for (int d = 0; d < 16; ++d) v[d] = s[d] * scale;

        if (it < 2) {   // final b-update is dead in the reference
            #pragma unroll
            for (int k = 0; k < 9; ++k) {
                float dot = V[k][0] * v[0];
                #pragma unroll
                for (int d = 1; d < 16; ++d) dot = fmaf(V[k][d], v[d], dot);
                b_log[k] += dot;
            }
        }
    }

    // ---------------- outputs ----------------
    if (c == 0) {
        float4* dst = reinterpret_cast<float4*>(out + (size_t)pos * 256 + n * 16);
        dst[0] = make_float4(v[0],  v[1],  v[2],  v[3]);
        dst[1] = make_float4(v[4],  v[5],  v[6],  v[7]);
        dst[2] = make_float4(v[8],  v[9],  v[10], v[11]);
        dst[3] = make_float4(v[12], v[13], v[14], v[15]);

        float m2 = 0.0f;
        #pragma unroll
        for (int d = 0; d < 16; ++d) m2 = fmaf(v[d], v[d], m2);
        const float sc2 = m2 / ((1.0f + m2) * sqrtf(m2 + CAPS_EPS));
        out[921600 + (size_t)pos * 16 + n] = sqrtf(m2 * sc2 * sc2 + CAPS_EPS);
    }
}

extern "C" void kernel_launch(void* const* d_in, const int* in_sizes, int n_in,
                              void* d_out, int out_size, void* d_ws, size_t ws_size,
                              hipStream_t stream) {
    const float* poses = (const float*)d_in[0];
    // d_in[1] = input_activations: unused by the reference computation
    const float* kern  = (const float*)d_in[2];
    float* out = (float*)d_out;

    caps_route<<<dim3(3600), dim3(256), 0, stream>>>(poses, kern, out);
}